// Round 1
// baseline (2200.606 us; speedup 1.0000x reference)
//
#include <hip/hip_runtime.h>
#include <hip/hip_bf16.h>

// ---------------------------------------------------------------------------
// RG-LRU block: T=8192, D_MODEL=768, D_RNN=1024, KW=4. All fp32 this round.
//   h  = x @ w1.T + b1                      (8192x2048)
//   ab = gelu_tanh(h[:, :1024]); bb = h[:, 1024:]
//   bc[t,o] = sum_k sum_i conv_w[o,i,k] * bb[t-3+k, i]   (causal conv)
//   g  = sigmoid(bc @ w_rg.T + b_rg)        (8192x2048)
//   a_t = exp(-8*softplus(Lambda)*rec_gate); gx = sqrt(1-a^2)*inp_gate*bc
//   y_t = a_t*y_{t-1} + gx_t  (chunked 3-phase scan)
//   out = (ab*y) @ w_out.T + b_out          (8192x768)
// ---------------------------------------------------------------------------

#define T_LEN 8192
#define DM 768
#define DR 1024
#define NC 128   // scan chunks
#define CL 64    // chunk length (NC*CL == T_LEN)

#define BM 64
#define BN 64
#define BK 16

// C[m,n] = sum_k A[m,k]*B[n,k] + bias[n].  A row-major (lda), B row-major (ldb=K).
// CONV variant: K==4096, A is bb (8192x1024); logical A[m, k] = bb[m + (k>>10) - 3, k&1023], 0 if row<0.
template<bool CONV>
__global__ __launch_bounds__(256)
void gemm_bt(const float* __restrict__ A, const float* __restrict__ B,
             const float* __restrict__ bias, float* __restrict__ C,
             int M, int N, int K, int lda, int ldc)
{
    __shared__ float As[BK][BM];
    __shared__ float Bs[BK][BN];
    const int tid = threadIdx.x;
    const int tx = tid & 15, ty = tid >> 4;
    const int m0 = blockIdx.y * BM, n0 = blockIdx.x * BN;
    const int arow = tid >> 2;          // 0..63 tile row for loading
    const int ac4  = (tid & 3) * 4;     // 0,4,8,12 k-offset for loading

    float acc[4][4] = {};

    for (int k0 = 0; k0 < K; k0 += BK) {
        float4 av, bv;
        if (CONV) {
            const int kk  = k0 + ac4;
            const int ksh = kk >> 10;       // constant within a 16-wide k-tile
            const int ii  = kk & 1023;
            const int row = m0 + arow + ksh - 3;
            av = (row >= 0) ? *(const float4*)&A[row * 1024 + ii]
                            : make_float4(0.f, 0.f, 0.f, 0.f);
        } else {
            av = *(const float4*)&A[(long)(m0 + arow) * lda + k0 + ac4];
        }
        bv = *(const float4*)&B[(long)(n0 + arow) * K + k0 + ac4];

        __syncthreads();   // previous iteration's LDS reads must finish
        As[ac4 + 0][arow] = av.x; As[ac4 + 1][arow] = av.y;
        As[ac4 + 2][arow] = av.z; As[ac4 + 3][arow] = av.w;
        Bs[ac4 + 0][arow] = bv.x; Bs[ac4 + 1][arow] = bv.y;
        Bs[ac4 + 2][arow] = bv.z; Bs[ac4 + 3][arow] = bv.w;
        __syncthreads();

        #pragma unroll
        for (int k = 0; k < BK; ++k) {
            float4 a4 = *(const float4*)&As[k][ty * 4];
            float4 b4 = *(const float4*)&Bs[k][tx * 4];
            float aa[4] = {a4.x, a4.y, a4.z, a4.w};
            float bb[4] = {b4.x, b4.y, b4.z, b4.w};
            #pragma unroll
            for (int i = 0; i < 4; ++i)
                #pragma unroll
                for (int j = 0; j < 4; ++j)
                    acc[i][j] = fmaf(aa[i], bb[j], acc[i][j]);
        }
    }

    #pragma unroll
    for (int i = 0; i < 4; ++i) {
        const int m = m0 + ty * 4 + i;
        #pragma unroll
        for (int j = 0; j < 4; ++j) {
            const int n = n0 + tx * 4 + j;
            float v = acc[i][j];
            if (bias) v += bias[n];
            C[(long)m * ldc + n] = v;
        }
    }
}

// conv_w (O=1024, I=1024, K=4) -> wbig[o][k*1024+i] (row-major 1024x4096)
__global__ void repack_conv(const float* __restrict__ w, float* __restrict__ wbig)
{
    const int n = blockIdx.x * 256 + threadIdx.x;   // 1024*4096 threads
    const int o = n >> 12;
    const int r = n & 4095;
    const int k = r >> 10;
    const int i = r & 1023;
    wbig[n] = w[o * 4096 + i * 4 + k];
}

// split h -> ab = gelu_tanh(h[:, :1024]), bb = h[:, 1024:]
__global__ void split_kernel(const float* __restrict__ h,
                             float* __restrict__ ab, float* __restrict__ bb)
{
    const long n = (long)blockIdx.x * 256 + threadIdx.x;   // T*1024
    const int t = (int)(n >> 10), c = (int)(n & 1023);
    const float x  = h[(long)t * 2048 + c];
    const float hb = h[(long)t * 2048 + 1024 + c];
    const float inner = 0.7978845608028654f * (x + 0.044715f * x * x * x);
    ab[n] = 0.5f * x * (1.f + tanhf(inner));
    bb[n] = hb;
}

// In-place on g (T x 2048): g[:, :1024] <- gx, g[:, 1024:] <- a_t
__global__ void gates_kernel(float* __restrict__ g, const float* __restrict__ bc,
                             const float* __restrict__ Lambda)
{
    const long n = (long)blockIdx.x * 256 + threadIdx.x;   // T*1024
    const int t = (int)(n >> 10), c = (int)(n & 1023);
    const long gi = (long)t * 2048 + c;
    const float ig = 1.f / (1.f + expf(-g[gi]));
    const float rg = 1.f / (1.f + expf(-g[gi + 1024]));
    const float cl = -8.f * log1pf(expf(Lambda[c]));   // -8*softplus(Lambda)
    const float a  = expf(cl * rg);
    const float gx = sqrtf(fmaxf(0.f, 1.f - a * a)) * ig * bc[n];
    g[gi]        = gx;
    g[gi + 1024] = a;
}

// Phase 1: per (channel, chunk) local scan from 0; store end-state h and a-product.
__global__ void scan_pass1(const float* __restrict__ g,
                           float* __restrict__ ch, float* __restrict__ ca)
{
    const int c = blockIdx.y * 256 + threadIdx.x;   // channel
    const int j = blockIdx.x;                       // chunk
    float h = 0.f, ap = 1.f;
    const int t0 = j * CL;
    for (int tt = 0; tt < CL; ++tt) {
        const long idx = (long)(t0 + tt) * 2048;
        const float a  = g[idx + 1024 + c];
        const float gx = g[idx + c];
        h  = fmaf(a, h, gx);
        ap *= a;
    }
    ch[j * 1024 + c] = h;
    ca[j * 1024 + c] = ap;
}

// Phase 2: serial combine across chunks per channel; ch[j] becomes carry-IN of chunk j.
__global__ void scan_combine(float* __restrict__ ch, const float* __restrict__ ca)
{
    const int c = blockIdx.x * 256 + threadIdx.x;   // 4 blocks x 256 = 1024 channels
    float carry = 0.f;
    for (int j = 0; j < NC; ++j) {
        const float hj = ch[j * 1024 + c];
        const float aj = ca[j * 1024 + c];
        ch[j * 1024 + c] = carry;
        carry = fmaf(aj, carry, hj);
    }
}

// Phase 3: rescan with correct carry; fuse z = ab * y.
__global__ void scan_pass2(const float* __restrict__ g, const float* __restrict__ carry_in,
                           const float* __restrict__ ab, float* __restrict__ z)
{
    const int c = blockIdx.y * 256 + threadIdx.x;
    const int j = blockIdx.x;
    float h = carry_in[j * 1024 + c];
    const int t0 = j * CL;
    for (int tt = 0; tt < CL; ++tt) {
        const int t = t0 + tt;
        const long idx = (long)t * 2048;
        const float a  = g[idx + 1024 + c];
        const float gx = g[idx + c];
        h = fmaf(a, h, gx);
        z[(long)t * 1024 + c] = ab[(long)t * 1024 + c] * h;
    }
}

extern "C" void kernel_launch(void* const* d_in, const int* in_sizes, int n_in,
                              void* d_out, int out_size, void* d_ws, size_t ws_size,
                              hipStream_t stream)
{
    const float* x      = (const float*)d_in[0];
    const float* w1     = (const float*)d_in[1];
    const float* b1     = (const float*)d_in[2];
    const float* conv_w = (const float*)d_in[3];
    const float* w_rg   = (const float*)d_in[4];
    const float* b_rg   = (const float*)d_in[5];
    const float* w_out  = (const float*)d_in[6];
    const float* b_out  = (const float*)d_in[7];
    const float* Lambda = (const float*)d_in[8];
    float* out = (float*)d_out;

    // workspace layout (floats); total ~46.4M floats ~= 186 MB
    float* ws   = (float*)d_ws;
    float* wbig = ws;                       // 1024*4096
    float* hbuf = wbig + 4194304;           // 8192*2048 (h, then reused for g/gx/a_t)
    float* ab   = hbuf + 16777216;          // 8192*1024
    float* bb   = ab   + 8388608;           // 8192*1024 (b_branch, then z)
    float* bc   = bb   + 8388608;           // 8192*1024
    float* ch   = bc   + 8388608;           // NC*1024
    float* ca   = ch   + NC * 1024;         // NC*1024
    (void)in_sizes; (void)n_in; (void)out_size; (void)ws_size;

    repack_conv<<<(1024 * 4096) / 256, 256, 0, stream>>>(conv_w, wbig);

    // h = x @ w1.T + b1
    {
        dim3 grid(2048 / BN, T_LEN / BM);
        gemm_bt<false><<<grid, 256, 0, stream>>>(x, w1, b1, hbuf,
                                                 T_LEN, 2048, DM, DM, 2048);
    }
    split_kernel<<<(T_LEN * DR) / 256, 256, 0, stream>>>(hbuf, ab, bb);

    // bc = causal conv as one GEMM over K=4096 with shifted rows of bb
    {
        dim3 grid(1024 / BN, T_LEN / BM);
        gemm_bt<true><<<grid, 256, 0, stream>>>(bb, wbig, nullptr, bc,
                                                T_LEN, DR, 4 * DR, DR, DR);
    }

    // g_pre = bc @ w_rg.T + b_rg  (into hbuf, h no longer needed)
    {
        dim3 grid(2048 / BN, T_LEN / BM);
        gemm_bt<false><<<grid, 256, 0, stream>>>(bc, w_rg, b_rg, hbuf,
                                                 T_LEN, 2048, DR, DR, 2048);
    }

    gates_kernel<<<(T_LEN * DR) / 256, 256, 0, stream>>>(hbuf, bc, Lambda);

    // chunked scan: y_t = a_t*y_{t-1} + gx_t ; z = ab*y  (z into bb)
    {
        dim3 gs(NC, DR / 256);
        scan_pass1<<<gs, 256, 0, stream>>>(hbuf, ch, ca);
        scan_combine<<<DR / 256, 256, 0, stream>>>(ch, ca);
        scan_pass2<<<gs, 256, 0, stream>>>(hbuf, ch, ab, bb);
    }

    // out = z @ w_out.T + b_out
    {
        dim3 grid(DM / BN, T_LEN / BM);
        gemm_bt<false><<<grid, 256, 0, stream>>>(bb, w_out, b_out, out,
                                                 T_LEN, DM, DR, DR, DM);
    }
}

// Round 2
// 479.302 us; speedup vs baseline: 4.5913x; 4.5913x over previous
//
#include <hip/hip_runtime.h>
#include <hip/hip_bf16.h>
#include <stdint.h>

// ---------------------------------------------------------------------------
// RG-LRU block: T=8192, D_MODEL=768, D_RNN=1024, KW=4.
// Round 2: all four GEMMs moved to bf16 MFMA (16x16x32), 128x128x32 tiles,
// global_load_lds width-16 staging (m97 structure), fp32 accumulate.
// Conv handled as one GEMM over K=4096 against a 3-row-zero-padded bb (bbp),
// so no boundary predication is needed in the staging path.
// ---------------------------------------------------------------------------

#define T_LEN 8192
#define DM 768
#define DR 1024
#define NC 128   // scan chunks
#define CL 64    // chunk length

typedef __bf16 bf16x8 __attribute__((ext_vector_type(8)));
typedef float  f32x4  __attribute__((ext_vector_type(4)));

#define AS1 __attribute__((address_space(1)))
#define AS3 __attribute__((address_space(3)))

__device__ __forceinline__ void cp16_g2l(const void* g, void* l) {
    __builtin_amdgcn_global_load_lds((const AS1 void*)g, (AS3 void*)l, 16, 0, 0);
}

// C[m,n] = sum_k A[m,k]*B[n,k] (+ bias[n]).  A: M x K bf16 row-major (lda),
// B: N x K bf16 row-major.  CONV: A is bbp (padded bb), logical
// A[m,k] = bbp[m + (k>>10)][k & 1023]  (bbp has 3 leading zero rows).
template<bool CONV, bool OUT_BF16>
__global__ __launch_bounds__(256)
void gemm_mfma(const __hip_bfloat16* __restrict__ A,
               const __hip_bfloat16* __restrict__ B,
               const float* __restrict__ bias,
               void* __restrict__ Cv,
               int K, int lda, int N)
{
    __shared__ __bf16 As[128 * 32];
    __shared__ __bf16 Bs[128 * 32];

    const int tid  = threadIdx.x;
    const int lane = tid & 63;
    const int wave = tid >> 6;
    const size_t m0 = (size_t)blockIdx.y * 128;
    const int    n0 = blockIdx.x * 128;
    const int wm = (wave >> 1) * 64;   // wave's 64x64 sub-tile
    const int wn = (wave & 1) * 64;

    f32x4 acc[4][4];
#pragma unroll
    for (int i = 0; i < 4; ++i)
#pragma unroll
        for (int j = 0; j < 4; ++j)
            acc[i][j] = f32x4{0.f, 0.f, 0.f, 0.f};

    const int fr = lane & 15;          // fragment row (m or n within 16)
    const int fk = (lane >> 4) * 8;    // fragment k offset

    for (int k0 = 0; k0 < K; k0 += 32) {
        const int ksh  = CONV ? (k0 >> 10) : 0;     // uniform within a k-tile
        const int kcol = CONV ? (k0 & 1023) : k0;

        __syncthreads();   // previous iteration's LDS reads complete
        // Stage A tile (128 rows x 32 cols bf16 = 8 KB = 512 x 16B chunks)
#pragma unroll
        for (int q = 0; q < 2; ++q) {
            const int lin = q * 256 + tid;          // chunk index
            const int rr  = lin >> 2;               // tile row
            const int cc  = (lin & 3) * 8;          // element col
            cp16_g2l(A + (m0 + rr + ksh) * (size_t)lda + kcol + cc, &As[lin * 8]);
        }
        // Stage B tile
#pragma unroll
        for (int q = 0; q < 2; ++q) {
            const int lin = q * 256 + tid;
            const int rr  = lin >> 2;
            const int cc  = (lin & 3) * 8;
            cp16_g2l(B + (size_t)(n0 + rr) * K + k0 + cc, &Bs[lin * 8]);
        }
        __syncthreads();   // vmcnt(0) drain -> tiles visible

        bf16x8 af[4], bfr[4];
#pragma unroll
        for (int mi = 0; mi < 4; ++mi)
            af[mi] = *(const bf16x8*)&As[(wm + mi * 16 + fr) * 32 + fk];
#pragma unroll
        for (int ni = 0; ni < 4; ++ni)
            bfr[ni] = *(const bf16x8*)&Bs[(wn + ni * 16 + fr) * 32 + fk];
#pragma unroll
        for (int mi = 0; mi < 4; ++mi)
#pragma unroll
            for (int ni = 0; ni < 4; ++ni)
                acc[mi][ni] = __builtin_amdgcn_mfma_f32_16x16x32_bf16(
                    af[mi], bfr[ni], acc[mi][ni], 0, 0, 0);
    }

    // Epilogue: C/D layout col = lane&15, row = (lane>>4)*4 + reg
    const int er = (lane >> 4) * 4;
    const int ec = lane & 15;
#pragma unroll
    for (int ni = 0; ni < 4; ++ni) {
        const int n = n0 + wn + ni * 16 + ec;
        const float bv = bias ? bias[n] : 0.f;
#pragma unroll
        for (int mi = 0; mi < 4; ++mi) {
#pragma unroll
            for (int r2 = 0; r2 < 4; ++r2) {
                const size_t m = m0 + wm + mi * 16 + er + r2;
                const float v = acc[mi][ni][r2] + bv;
                if (OUT_BF16)
                    ((__hip_bfloat16*)Cv)[m * (size_t)N + n] = __float2bfloat16(v);
                else
                    ((float*)Cv)[m * (size_t)N + n] = v;
            }
        }
    }
}

// fp32 -> bf16 convert
__global__ void f2b(const float* __restrict__ src, __hip_bfloat16* __restrict__ dst)
{
    const int n = blockIdx.x * 256 + threadIdx.x;
    dst[n] = __float2bfloat16(src[n]);
}

// conv_w (O=1024, I=1024, K=4) -> wbigb[o][k*1024+i] bf16 (1024 x 4096)
__global__ void repack_conv(const float* __restrict__ w, __hip_bfloat16* __restrict__ wbigb)
{
    const int n = blockIdx.x * 256 + threadIdx.x;   // 1024*4096
    const int o = n >> 12;
    const int r = n & 4095;
    const int k = r >> 10;
    const int i = r & 1023;
    wbigb[n] = __float2bfloat16(w[o * 4096 + i * 4 + k]);
}

// h (T x 2048 fp32) -> ab = gelu_tanh(h[:, :1024]) fp32; bbp bf16 with 3 zero rows.
__global__ void split_kernel(const float* __restrict__ h,
                             float* __restrict__ ab, __hip_bfloat16* __restrict__ bbp)
{
    const long n = (long)blockIdx.x * 256 + threadIdx.x;   // (T+3)*1024
    const int t = (int)(n >> 10), c = (int)(n & 1023);
    if (t < 3) { bbp[n] = __float2bfloat16(0.f); return; }
    const int ts = t - 3;
    const float x  = h[(long)ts * 2048 + c];
    const float hb = h[(long)ts * 2048 + 1024 + c];
    const float inner = 0.7978845608028654f * (x + 0.044715f * x * x * x);
    ab[(long)ts * 1024 + c] = 0.5f * x * (1.f + tanhf(inner));
    bbp[n] = __float2bfloat16(hb);
}

// In-place on g (T x 2048 fp32): g[:, :1024] <- gx, g[:, 1024:] <- a_t
__global__ void gates_kernel(float* __restrict__ g, const __hip_bfloat16* __restrict__ bc,
                             const float* __restrict__ Lambda)
{
    const long n = (long)blockIdx.x * 256 + threadIdx.x;   // T*1024
    const int t = (int)(n >> 10), c = (int)(n & 1023);
    const long gi = (long)t * 2048 + c;
    const float ig = 1.f / (1.f + expf(-g[gi]));
    const float rg = 1.f / (1.f + expf(-g[gi + 1024]));
    const float cl = -8.f * log1pf(expf(Lambda[c]));   // -8*softplus(Lambda)
    const float a  = expf(cl * rg);
    const float gx = sqrtf(fmaxf(0.f, 1.f - a * a)) * ig * __bfloat162float(bc[n]);
    g[gi]        = gx;
    g[gi + 1024] = a;
}

// Phase 1: per (channel, chunk) local scan from 0; store end-state h and a-product.
__global__ void scan_pass1(const float* __restrict__ g,
                           float* __restrict__ ch, float* __restrict__ ca)
{
    const int c = blockIdx.y * 256 + threadIdx.x;
    const int j = blockIdx.x;
    float h = 0.f, ap = 1.f;
    const int t0 = j * CL;
    for (int tt = 0; tt < CL; ++tt) {
        const long idx = (long)(t0 + tt) * 2048;
        const float a  = g[idx + 1024 + c];
        const float gx = g[idx + c];
        h  = fmaf(a, h, gx);
        ap *= a;
    }
    ch[j * 1024 + c] = h;
    ca[j * 1024 + c] = ap;
}

// Phase 2: serial combine across chunks; ch[j] becomes carry-IN of chunk j.
__global__ void scan_combine(float* __restrict__ ch, const float* __restrict__ ca)
{
    const int c = blockIdx.x * 256 + threadIdx.x;
    float carry = 0.f;
    for (int j = 0; j < NC; ++j) {
        const float hj = ch[j * 1024 + c];
        const float aj = ca[j * 1024 + c];
        ch[j * 1024 + c] = carry;
        carry = fmaf(aj, carry, hj);
    }
}

// Phase 3: rescan with carry; fuse z = ab * y -> bf16 (GEMM-A for out proj).
__global__ void scan_pass2(const float* __restrict__ g, const float* __restrict__ carry_in,
                           const float* __restrict__ ab, __hip_bfloat16* __restrict__ zb)
{
    const int c = blockIdx.y * 256 + threadIdx.x;
    const int j = blockIdx.x;
    float h = carry_in[j * 1024 + c];
    const int t0 = j * CL;
    for (int tt = 0; tt < CL; ++tt) {
        const int t = t0 + tt;
        const long idx = (long)t * 2048;
        const float a  = g[idx + 1024 + c];
        const float gx = g[idx + c];
        h = fmaf(a, h, gx);
        zb[(long)t * 1024 + c] = __float2bfloat16(ab[(long)t * 1024 + c] * h);
    }
}

extern "C" void kernel_launch(void* const* d_in, const int* in_sizes, int n_in,
                              void* d_out, int out_size, void* d_ws, size_t ws_size,
                              hipStream_t stream)
{
    const float* x      = (const float*)d_in[0];
    const float* w1     = (const float*)d_in[1];
    const float* b1     = (const float*)d_in[2];
    const float* conv_w = (const float*)d_in[3];
    const float* w_rg   = (const float*)d_in[4];
    const float* b_rg   = (const float*)d_in[5];
    const float* w_out  = (const float*)d_in[6];
    const float* b_out  = (const float*)d_in[7];
    const float* Lambda = (const float*)d_in[8];
    float* out = (float*)d_out;
    (void)in_sizes; (void)n_in; (void)out_size; (void)ws_size;

    // ---- workspace layout (~158 MB; round-1 proved >=186 MB available) ----
    char* p = (char*)d_ws;
    auto alloc = [&](size_t bytes) { char* r = p; p += (bytes + 255) & ~255ULL; return r; };
    float*          hbuf  = (float*)alloc(8192ULL * 2048 * 4);   // 64 MB (h, then g)
    float*          ab    = (float*)alloc(8192ULL * 1024 * 4);   // 32 MB
    __hip_bfloat16* bbp   = (__hip_bfloat16*)alloc(8200ULL * 1024 * 2); // 16.8 MB
    __hip_bfloat16* bcb   = (__hip_bfloat16*)alloc(8192ULL * 1024 * 2); // 16 MB (later zb)
    __hip_bfloat16* wbigb = (__hip_bfloat16*)alloc(1024ULL * 4096 * 2); // 8 MB
    __hip_bfloat16* xb    = (__hip_bfloat16*)alloc(8192ULL * 768 * 2);  // 12 MB
    __hip_bfloat16* w1b   = (__hip_bfloat16*)alloc(2048ULL * 768 * 2);  // 3 MB
    __hip_bfloat16* w_rgb = (__hip_bfloat16*)alloc(2048ULL * 1024 * 2); // 4 MB
    __hip_bfloat16* w_outb= (__hip_bfloat16*)alloc(768ULL * 1024 * 2);  // 1.5 MB
    float*          chv   = (float*)alloc(NC * 1024ULL * 4);
    float*          cav   = (float*)alloc(NC * 1024ULL * 4);
    __hip_bfloat16* zb    = bcb;   // overlay: bcb dead after gates_kernel

    // ---- bf16 conversions ----
    f2b<<<(8192 * 768) / 256, 256, 0, stream>>>(x, xb);
    f2b<<<(2048 * 768) / 256, 256, 0, stream>>>(w1, w1b);
    f2b<<<(2048 * 1024) / 256, 256, 0, stream>>>(w_rg, w_rgb);
    f2b<<<(768 * 1024) / 256, 256, 0, stream>>>(w_out, w_outb);
    repack_conv<<<(1024 * 4096) / 256, 256, 0, stream>>>(conv_w, wbigb);

    // h = x @ w1.T + b1   (M=8192, N=2048, K=768) -> fp32
    {
        dim3 grid(2048 / 128, T_LEN / 128);
        gemm_mfma<false, false><<<grid, 256, 0, stream>>>(xb, w1b, b1, hbuf, DM, DM, 2048);
    }

    // ab = gelu(h[:, :1024]); bbp = pad3(bf16(h[:, 1024:]))
    split_kernel<<<((T_LEN + 3) * DR) / 256, 256, 0, stream>>>(hbuf, ab, bbp);

    // bc = causal conv as GEMM  (M=8192, N=1024, K=4096) -> bf16
    {
        dim3 grid(1024 / 128, T_LEN / 128);
        gemm_mfma<true, true><<<grid, 256, 0, stream>>>(bbp, wbigb, nullptr, bcb, 4 * DR, DR, DR);
    }

    // g_pre = bc @ w_rg.T + b_rg  (M=8192, N=2048, K=1024) -> fp32
    {
        dim3 grid(2048 / 128, T_LEN / 128);
        gemm_mfma<false, false><<<grid, 256, 0, stream>>>(bcb, w_rgb, b_rg, hbuf, DR, DR, 2048);
    }

    // gates: hbuf[:, :1024] <- gx, hbuf[:, 1024:] <- a_t
    gates_kernel<<<(T_LEN * DR) / 256, 256, 0, stream>>>(hbuf, bcb, Lambda);

    // chunked scan; z = ab*y -> bf16 (overlays bcb)
    {
        dim3 gs(NC, DR / 256);
        scan_pass1<<<gs, 256, 0, stream>>>(hbuf, chv, cav);
        scan_combine<<<DR / 256, 256, 0, stream>>>(chv, cav);
        scan_pass2<<<gs, 256, 0, stream>>>(hbuf, chv, ab, zb);
    }

    // out = z @ w_out.T + b_out  (M=8192, N=768, K=1024) -> fp32
    {
        dim3 grid(DM / 128, T_LEN / 128);
        gemm_mfma<false, false><<<grid, 256, 0, stream>>>(zb, w_outb, b_out, out, DR, DR, DM);
    }
}

// Round 3
// 444.410 us; speedup vs baseline: 4.9518x; 1.0785x over previous
//
#include <hip/hip_runtime.h>
#include <hip/hip_bf16.h>
#include <stdint.h>

// ---------------------------------------------------------------------------
// RG-LRU block: T=8192, D_MODEL=768, D_RNN=1024, KW=4.
// Round 3:
//  - XCD-aware grid: blockIdx.x = row-block (M), blockIdx.y = col-block (N).
//    flat = row + gridX*col -> XCD = row%8, so all col-blocks sharing an
//    A-tile co-reside on one XCD (A lives in that XCD's L2; B via L3).
//  - h-GEMM epilogue fused: writes ab=bf16(gelu(h1)) and bbp=bf16(h2) directly.
//  - gates fused into scan passes (recompute sigmoid/exp from g_pre + bc).
// ---------------------------------------------------------------------------

#define T_LEN 8192
#define DM 768
#define DR 1024
#define NC 128   // scan chunks
#define CL 64    // chunk length

typedef __bf16 bf16x8 __attribute__((ext_vector_type(8)));
typedef float  f32x4  __attribute__((ext_vector_type(4)));

#define AS1 __attribute__((address_space(1)))
#define AS3 __attribute__((address_space(3)))

__device__ __forceinline__ void cp16_g2l(const void* g, void* l) {
    __builtin_amdgcn_global_load_lds((const AS1 void*)g, (AS3 void*)l, 16, 0, 0);
}

__device__ __forceinline__ float gelu_tanh(float x) {
    const float inner = 0.7978845608028654f * (x + 0.044715f * x * x * x);
    return 0.5f * x * (1.f + tanhf(inner));
}

// C[m,n] = sum_k A[m,k]*B[n,k] (+ bias[n]).  A: M x K bf16 row-major (lda),
// B: N x K bf16 row-major.
// CONV: logical A[m,k] = bbp[m + (k>>10)][k & 1023] (bbp = 3-zero-row-padded bb).
// EPI: 0 = fp32 +bias -> Cv(float*, ld N)
//      1 = bf16 no-bias -> Cv(bf16*, ld N)
//      2 = split: n<1024 -> ab=bf16(gelu(v+bias)); n>=1024 -> bbp[(m+3),n-1024]=bf16(v+bias)
template<bool CONV, int EPI>
__global__ __launch_bounds__(256)
void gemm_mfma(const __hip_bfloat16* __restrict__ A,
               const __hip_bfloat16* __restrict__ B,
               const float* __restrict__ bias,
               void* __restrict__ Cv,
               int K, int lda, int N,
               __hip_bfloat16* __restrict__ D2)
{
    __shared__ __bf16 As[128 * 32];
    __shared__ __bf16 Bs[128 * 32];

    const int tid  = threadIdx.x;
    const int lane = tid & 63;
    const int wave = tid >> 6;
    const size_t m0 = (size_t)blockIdx.x * 128;   // row-block (XCD = blockIdx.x % 8)
    const int    n0 = blockIdx.y * 128;           // col-block
    const int wm = (wave >> 1) * 64;
    const int wn = (wave & 1) * 64;

    f32x4 acc[4][4];
#pragma unroll
    for (int i = 0; i < 4; ++i)
#pragma unroll
        for (int j = 0; j < 4; ++j)
            acc[i][j] = f32x4{0.f, 0.f, 0.f, 0.f};

    const int fr = lane & 15;          // fragment row
    const int fk = (lane >> 4) * 8;    // fragment k offset

    for (int k0 = 0; k0 < K; k0 += 32) {
        const int ksh  = CONV ? (k0 >> 10) : 0;     // uniform within a k-tile
        const int kcol = CONV ? (k0 & 1023) : k0;

        __syncthreads();
#pragma unroll
        for (int q = 0; q < 2; ++q) {
            const int lin = q * 256 + tid;
            const int rr  = lin >> 2;
            const int cc  = (lin & 3) * 8;
            cp16_g2l(A + (m0 + rr + ksh) * (size_t)lda + kcol + cc, &As[lin * 8]);
        }
#pragma unroll
        for (int q = 0; q < 2; ++q) {
            const int lin = q * 256 + tid;
            const int rr  = lin >> 2;
            const int cc  = (lin & 3) * 8;
            cp16_g2l(B + (size_t)(n0 + rr) * K + k0 + cc, &Bs[lin * 8]);
        }
        __syncthreads();

        bf16x8 af[4], bfr[4];
#pragma unroll
        for (int mi = 0; mi < 4; ++mi)
            af[mi] = *(const bf16x8*)&As[(wm + mi * 16 + fr) * 32 + fk];
#pragma unroll
        for (int ni = 0; ni < 4; ++ni)
            bfr[ni] = *(const bf16x8*)&Bs[(wn + ni * 16 + fr) * 32 + fk];
#pragma unroll
        for (int mi = 0; mi < 4; ++mi)
#pragma unroll
            for (int ni = 0; ni < 4; ++ni)
                acc[mi][ni] = __builtin_amdgcn_mfma_f32_16x16x32_bf16(
                    af[mi], bfr[ni], acc[mi][ni], 0, 0, 0);
    }

    // C/D layout: col = lane&15, row = (lane>>4)*4 + reg
    const int er = (lane >> 4) * 4;
    const int ec = lane & 15;
#pragma unroll
    for (int ni = 0; ni < 4; ++ni) {
        const int n = n0 + wn + ni * 16 + ec;
        const float bv = bias ? bias[n] : 0.f;
#pragma unroll
        for (int mi = 0; mi < 4; ++mi) {
#pragma unroll
            for (int r2 = 0; r2 < 4; ++r2) {
                const size_t m = m0 + wm + mi * 16 + er + r2;
                const float v = acc[mi][ni][r2] + bv;
                if (EPI == 0) {
                    ((float*)Cv)[m * (size_t)N + n] = v;
                } else if (EPI == 1) {
                    ((__hip_bfloat16*)Cv)[m * (size_t)N + n] = __float2bfloat16(v);
                } else {
                    if (n < 1024)
                        ((__hip_bfloat16*)Cv)[m * 1024 + n] = __float2bfloat16(gelu_tanh(v));
                    else
                        D2[(m + 3) * 1024 + (n - 1024)] = __float2bfloat16(v);
                }
            }
        }
    }
}

// fp32 -> bf16 convert
__global__ void f2b(const float* __restrict__ src, __hip_bfloat16* __restrict__ dst)
{
    const int n = blockIdx.x * 256 + threadIdx.x;
    dst[n] = __float2bfloat16(src[n]);
}

// conv_w (O=1024, I=1024, K=4) -> wbigb[o][k*1024+i] bf16 (1024 x 4096)
__global__ void repack_conv(const float* __restrict__ w, __hip_bfloat16* __restrict__ wbigb)
{
    const int n = blockIdx.x * 256 + threadIdx.x;
    const int o = n >> 12;
    const int r = n & 4095;
    const int k = r >> 10;
    const int i = r & 1023;
    wbigb[n] = __float2bfloat16(w[o * 4096 + i * 4 + k]);
}

// zero the 3 leading pad rows of bbp
__global__ void zero_pad(__hip_bfloat16* __restrict__ bbp)
{
    const int n = blockIdx.x * 256 + threadIdx.x;   // 3072
    bbp[n] = __float2bfloat16(0.f);
}

// Gates recomputed inline from g_pre (T x 2048 fp32) + bc (bf16):
//   ig = sigmoid(g_pre[t, c]); rg = sigmoid(g_pre[t, 1024+c])
//   a = exp(-8*softplus(Lambda[c]) * rg); gx = sqrt(1-a^2)*ig*bc[t,c]
__global__ void scan_pass1(const float* __restrict__ gp, const __hip_bfloat16* __restrict__ bc,
                           const float* __restrict__ Lambda,
                           float* __restrict__ ch, float* __restrict__ ca)
{
    const int c = blockIdx.y * 256 + threadIdx.x;
    const int j = blockIdx.x;
    const float cl = -8.f * log1pf(expf(Lambda[c]));
    float h = 0.f, ap = 1.f;
    const int t0 = j * CL;
    for (int tt = 0; tt < CL; ++tt) {
        const int t = t0 + tt;
        const long gi = (long)t * 2048 + c;
        const float ig = 1.f / (1.f + expf(-gp[gi]));
        const float rg = 1.f / (1.f + expf(-gp[gi + 1024]));
        const float a  = expf(cl * rg);
        const float gx = sqrtf(fmaxf(0.f, 1.f - a * a)) * ig *
                         __bfloat162float(bc[(long)t * 1024 + c]);
        h  = fmaf(a, h, gx);
        ap *= a;
    }
    ch[j * 1024 + c] = h;
    ca[j * 1024 + c] = ap;
}

__global__ void scan_combine(float* __restrict__ ch, const float* __restrict__ ca)
{
    const int c = blockIdx.x * 256 + threadIdx.x;
    float carry = 0.f;
    for (int j = 0; j < NC; ++j) {
        const float hj = ch[j * 1024 + c];
        const float aj = ca[j * 1024 + c];
        ch[j * 1024 + c] = carry;
        carry = fmaf(aj, carry, hj);
    }
}

// Rescan with carry; z = ab * y -> bf16.  NOTE: zb aliases bc (read-then-write
// of the same element within one thread; no cross-thread hazard).
__global__ void scan_pass2(const float* __restrict__ gp, const __hip_bfloat16* bc,
                           const float* __restrict__ Lambda,
                           const float* __restrict__ carry_in,
                           const __hip_bfloat16* __restrict__ ab,
                           __hip_bfloat16* zb)
{
    const int c = blockIdx.y * 256 + threadIdx.x;
    const int j = blockIdx.x;
    const float cl = -8.f * log1pf(expf(Lambda[c]));
    float h = carry_in[j * 1024 + c];
    const int t0 = j * CL;
    for (int tt = 0; tt < CL; ++tt) {
        const int t = t0 + tt;
        const long gi = (long)t * 2048 + c;
        const long bi = (long)t * 1024 + c;
        const float ig = 1.f / (1.f + expf(-gp[gi]));
        const float rg = 1.f / (1.f + expf(-gp[gi + 1024]));
        const float a  = expf(cl * rg);
        const float gx = sqrtf(fmaxf(0.f, 1.f - a * a)) * ig * __bfloat162float(bc[bi]);
        h = fmaf(a, h, gx);
        zb[bi] = __float2bfloat16(__bfloat162float(ab[bi]) * h);
    }
}

extern "C" void kernel_launch(void* const* d_in, const int* in_sizes, int n_in,
                              void* d_out, int out_size, void* d_ws, size_t ws_size,
                              hipStream_t stream)
{
    const float* x      = (const float*)d_in[0];
    const float* w1     = (const float*)d_in[1];
    const float* b1     = (const float*)d_in[2];
    const float* conv_w = (const float*)d_in[3];
    const float* w_rg   = (const float*)d_in[4];
    const float* b_rg   = (const float*)d_in[5];
    const float* w_out  = (const float*)d_in[6];
    const float* b_out  = (const float*)d_in[7];
    const float* Lambda = (const float*)d_in[8];
    float* out = (float*)d_out;
    (void)in_sizes; (void)n_in; (void)out_size; (void)ws_size;

    // ---- workspace layout (~142 MB) ----
    char* p = (char*)d_ws;
    auto alloc = [&](size_t bytes) { char* r = p; p += (bytes + 255) & ~255ULL; return r; };
    float*          gpre  = (float*)alloc(8192ULL * 2048 * 4);          // 64 MB
    __hip_bfloat16* ab    = (__hip_bfloat16*)alloc(8192ULL * 1024 * 2); // 16 MB
    __hip_bfloat16* bbp   = (__hip_bfloat16*)alloc(8200ULL * 1024 * 2); // 16.8 MB
    __hip_bfloat16* bcb   = (__hip_bfloat16*)alloc(8192ULL * 1024 * 2); // 16 MB (later zb)
    __hip_bfloat16* wbigb = (__hip_bfloat16*)alloc(1024ULL * 4096 * 2); // 8 MB
    __hip_bfloat16* xb    = (__hip_bfloat16*)alloc(8192ULL * 768 * 2);  // 12 MB
    __hip_bfloat16* w1b   = (__hip_bfloat16*)alloc(2048ULL * 768 * 2);  // 3 MB
    __hip_bfloat16* w_rgb = (__hip_bfloat16*)alloc(2048ULL * 1024 * 2); // 4 MB
    __hip_bfloat16* w_outb= (__hip_bfloat16*)alloc(768ULL * 1024 * 2);  // 1.5 MB
    float*          chv   = (float*)alloc(NC * 1024ULL * 4);
    float*          cav   = (float*)alloc(NC * 1024ULL * 4);
    __hip_bfloat16* zb    = bcb;   // overlay

    // ---- bf16 conversions ----
    f2b<<<(8192 * 768) / 256, 256, 0, stream>>>(x, xb);
    f2b<<<(2048 * 768) / 256, 256, 0, stream>>>(w1, w1b);
    f2b<<<(2048 * 1024) / 256, 256, 0, stream>>>(w_rg, w_rgb);
    f2b<<<(768 * 1024) / 256, 256, 0, stream>>>(w_out, w_outb);
    repack_conv<<<(1024 * 4096) / 256, 256, 0, stream>>>(conv_w, wbigb);
    zero_pad<<<12, 256, 0, stream>>>(bbp);

    // h = x @ w1.T + b1, fused split: ab = bf16(gelu), bbp = bf16 (rows +3)
    {
        dim3 grid(T_LEN / 128, 2048 / 128);   // (rows, cols) -> XCD = row%8
        gemm_mfma<false, 2><<<grid, 256, 0, stream>>>(xb, w1b, b1, ab, DM, DM, 2048, bbp);
    }

    // bc = causal conv as GEMM (M=8192, N=1024, K=4096) -> bf16
    {
        dim3 grid(T_LEN / 128, 1024 / 128);
        gemm_mfma<true, 1><<<grid, 256, 0, stream>>>(bbp, wbigb, nullptr, bcb, 4 * DR, DR, DR, nullptr);
    }

    // g_pre = bc @ w_rg.T + b_rg -> fp32
    {
        dim3 grid(T_LEN / 128, 2048 / 128);
        gemm_mfma<false, 0><<<grid, 256, 0, stream>>>(bcb, w_rgb, b_rg, gpre, DR, DR, 2048, nullptr);
    }

    // chunked scan with fused gates; z = ab*y -> bf16 (overlays bcb)
    {
        dim3 gs(NC, DR / 256);
        scan_pass1<<<gs, 256, 0, stream>>>(gpre, bcb, Lambda, chv, cav);
        scan_combine<<<DR / 256, 256, 0, stream>>>(chv, cav);
        scan_pass2<<<gs, 256, 0, stream>>>(gpre, bcb, Lambda, chv, ab, zb);
    }

    // out = z @ w_out.T + b_out -> fp32
    {
        dim3 grid(T_LEN / 128, DM / 128);
        gemm_mfma<false, 0><<<grid, 256, 0, stream>>>(zb, w_outb, b_out, out, DR, DR, DM, nullptr);
    }
}

// Round 4
// 432.280 us; speedup vs baseline: 5.0907x; 1.0281x over previous
//
#include <hip/hip_runtime.h>
#include <hip/hip_bf16.h>
#include <stdint.h>

// ---------------------------------------------------------------------------
// RG-LRU block: T=8192, D_MODEL=768, D_RNN=1024, KW=4.
// Round 4:
//  - LDS XOR swizzle (16B-chunk ^ (row>>1)&3) at staging + fragment read:
//    kills the 8-way bank conflict (8.4M conflict cycles/dispatch in r3).
//  - g_pre stored bf16 (rg-GEMM epilogue converts, +bias) -> scan traffic halved.
//  - all input conversions fused into ONE prep kernel (launch-gap reduction).
//  - XCD-aware grid (blockIdx.x = M-block) kept from r3.
// ---------------------------------------------------------------------------

#define T_LEN 8192
#define DM 768
#define DR 1024
#define NC 128   // scan chunks
#define CL 64    // chunk length

typedef __bf16 bf16x8 __attribute__((ext_vector_type(8)));
typedef float  f32x4  __attribute__((ext_vector_type(4)));

#define AS1 __attribute__((address_space(1)))
#define AS3 __attribute__((address_space(3)))

__device__ __forceinline__ void cp16_g2l(const void* g, void* l) {
    __builtin_amdgcn_global_load_lds((const AS1 void*)g, (AS3 void*)l, 16, 0, 0);
}

__device__ __forceinline__ float gelu_tanh(float x) {
    const float inner = 0.7978845608028654f * (x + 0.044715f * x * x * x);
    return 0.5f * x * (1.f + tanhf(inner));
}

// C[m,n] = sum_k A[m,k]*B[n,k] (+ bias[n]).  A: M x K bf16 row-major (lda),
// B: N x K bf16 row-major.
// CONV: logical A[m,k] = bbp[m + (k>>10)][k & 1023] (bbp = 3-zero-row-padded bb).
// EPI: 0 = fp32 (+bias) -> Cv(float*, ld N)
//      1 = bf16 (+bias if non-null) -> Cv(bf16*, ld N)
//      2 = split: n<1024 -> Cv=bf16(gelu(v+bias)); n>=1024 -> D2[(m+3),n-1024]=bf16(v+bias)
template<bool CONV, int EPI>
__global__ __launch_bounds__(256)
void gemm_mfma(const __hip_bfloat16* __restrict__ A,
               const __hip_bfloat16* __restrict__ B,
               const float* __restrict__ bias,
               void* __restrict__ Cv,
               int K, int lda, int N,
               __hip_bfloat16* __restrict__ D2)
{
    __shared__ __bf16 As[128 * 32];
    __shared__ __bf16 Bs[128 * 32];

    const int tid  = threadIdx.x;
    const int lane = tid & 63;
    const int wave = tid >> 6;
    const size_t m0 = (size_t)blockIdx.x * 128;   // M-block (XCD = blockIdx.x % 8)
    const int    n0 = blockIdx.y * 128;
    const int wm = (wave >> 1) * 64;
    const int wn = (wave & 1) * 64;

    f32x4 acc[4][4];
#pragma unroll
    for (int i = 0; i < 4; ++i)
#pragma unroll
        for (int j = 0; j < 4; ++j)
            acc[i][j] = f32x4{0.f, 0.f, 0.f, 0.f};

    const int frow = lane & 15;
    const int fq   = lane >> 4;        // 16B-chunk index this lane consumes

    for (int k0 = 0; k0 < K; k0 += 32) {
        const int ksh  = CONV ? (k0 >> 10) : 0;     // uniform within a k-tile
        const int kcol = CONV ? (k0 & 1023) : k0;

        __syncthreads();
        // Staging: chunk (rr, cc) in LDS holds global chunk cc ^ ((rr>>1)&3).
#pragma unroll
        for (int q = 0; q < 2; ++q) {
            const int lin = q * 256 + tid;
            const int rr  = lin >> 2;
            const int cs  = ((lin & 3) ^ ((rr >> 1) & 3)) * 8;
            cp16_g2l(A + (m0 + rr + ksh) * (size_t)lda + kcol + cs, &As[lin * 8]);
        }
#pragma unroll
        for (int q = 0; q < 2; ++q) {
            const int lin = q * 256 + tid;
            const int rr  = lin >> 2;
            const int cs  = ((lin & 3) ^ ((rr >> 1) & 3)) * 8;
            cp16_g2l(B + (size_t)(n0 + rr) * K + k0 + cs, &Bs[lin * 8]);
        }
        __syncthreads();

        bf16x8 af[4], bfr[4];
#pragma unroll
        for (int mi = 0; mi < 4; ++mi) {
            const int R = wm + mi * 16 + frow;
            af[mi] = *(const bf16x8*)&As[R * 32 + ((fq ^ ((R >> 1) & 3)) * 8)];
        }
#pragma unroll
        for (int ni = 0; ni < 4; ++ni) {
            const int R = wn + ni * 16 + frow;
            bfr[ni] = *(const bf16x8*)&Bs[R * 32 + ((fq ^ ((R >> 1) & 3)) * 8)];
        }
#pragma unroll
        for (int mi = 0; mi < 4; ++mi)
#pragma unroll
            for (int ni = 0; ni < 4; ++ni)
                acc[mi][ni] = __builtin_amdgcn_mfma_f32_16x16x32_bf16(
                    af[mi], bfr[ni], acc[mi][ni], 0, 0, 0);
    }

    // C/D layout: col = lane&15, row = (lane>>4)*4 + reg
    const int er = fq * 4;
    const int ec = frow;
#pragma unroll
    for (int ni = 0; ni < 4; ++ni) {
        const int n = n0 + wn + ni * 16 + ec;
        const float bv = bias ? bias[n] : 0.f;
#pragma unroll
        for (int mi = 0; mi < 4; ++mi) {
#pragma unroll
            for (int r2 = 0; r2 < 4; ++r2) {
                const size_t m = m0 + wm + mi * 16 + er + r2;
                const float v = acc[mi][ni][r2] + bv;
                if (EPI == 0) {
                    ((float*)Cv)[m * (size_t)N + n] = v;
                } else if (EPI == 1) {
                    ((__hip_bfloat16*)Cv)[m * (size_t)N + n] = __float2bfloat16(v);
                } else {
                    if (n < 1024)
                        ((__hip_bfloat16*)Cv)[m * 1024 + n] = __float2bfloat16(gelu_tanh(v));
                    else
                        D2[(m + 3) * 1024 + (n - 1024)] = __float2bfloat16(v);
                }
            }
        }
    }
}

// One prep kernel: xb, w1b, w_rgb, w_outb conversions + conv repack + bbp pad zero.
#define PREP_X   6291456            // 8192*768
#define PREP_W1  (PREP_X + 1572864) // + 2048*768
#define PREP_WRG (PREP_W1 + 2097152)// + 2048*1024
#define PREP_WO  (PREP_WRG + 786432)// + 768*1024
#define PREP_CW  (PREP_WO + 4194304)// + 1024*4096
#define PREP_TOT (PREP_CW + 3072)   // + pad rows
__global__ void prep_kernel(const float* __restrict__ x, const float* __restrict__ w1,
                            const float* __restrict__ w_rg, const float* __restrict__ w_out,
                            const float* __restrict__ conv_w,
                            __hip_bfloat16* __restrict__ xb, __hip_bfloat16* __restrict__ w1b,
                            __hip_bfloat16* __restrict__ w_rgb, __hip_bfloat16* __restrict__ w_outb,
                            __hip_bfloat16* __restrict__ wbigb, __hip_bfloat16* __restrict__ bbp)
{
    const int idx = blockIdx.x * 256 + threadIdx.x;
    if (idx < PREP_X) {
        xb[idx] = __float2bfloat16(x[idx]);
    } else if (idx < PREP_W1) {
        const int i = idx - PREP_X;  w1b[i] = __float2bfloat16(w1[i]);
    } else if (idx < PREP_WRG) {
        const int i = idx - PREP_W1; w_rgb[i] = __float2bfloat16(w_rg[i]);
    } else if (idx < PREP_WO) {
        const int i = idx - PREP_WRG; w_outb[i] = __float2bfloat16(w_out[i]);
    } else if (idx < PREP_CW) {
        const int n = idx - PREP_WO;
        const int o = n >> 12, r = n & 4095, k = r >> 10, i = r & 1023;
        wbigb[n] = __float2bfloat16(conv_w[o * 4096 + i * 4 + k]);
    } else {
        bbp[idx - PREP_CW] = __float2bfloat16(0.f);
    }
}

// Gates recomputed inline from g_pre (T x 2048 bf16) + bc (bf16):
__global__ void scan_pass1(const __hip_bfloat16* __restrict__ gp,
                           const __hip_bfloat16* __restrict__ bc,
                           const float* __restrict__ Lambda,
                           float* __restrict__ ch, float* __restrict__ ca)
{
    const int c = blockIdx.y * 256 + threadIdx.x;
    const int j = blockIdx.x;
    const float cl = -8.f * log1pf(expf(Lambda[c]));
    float h = 0.f, ap = 1.f;
    const int t0 = j * CL;
    for (int tt = 0; tt < CL; ++tt) {
        const int t = t0 + tt;
        const long gi = (long)t * 2048 + c;
        const float ig = 1.f / (1.f + expf(-__bfloat162float(gp[gi])));
        const float rg = 1.f / (1.f + expf(-__bfloat162float(gp[gi + 1024])));
        const float a  = expf(cl * rg);
        const float gx = sqrtf(fmaxf(0.f, 1.f - a * a)) * ig *
                         __bfloat162float(bc[(long)t * 1024 + c]);
        h  = fmaf(a, h, gx);
        ap *= a;
    }
    ch[j * 1024 + c] = h;
    ca[j * 1024 + c] = ap;
}

__global__ void scan_combine(float* __restrict__ ch, const float* __restrict__ ca)
{
    const int c = blockIdx.x * 256 + threadIdx.x;
    float carry = 0.f;
    for (int j = 0; j < NC; ++j) {
        const float hj = ch[j * 1024 + c];
        const float aj = ca[j * 1024 + c];
        ch[j * 1024 + c] = carry;
        carry = fmaf(aj, carry, hj);
    }
}

// Rescan with carry; z = ab * y -> bf16 (zb aliases bc: same-element RMW per thread).
__global__ void scan_pass2(const __hip_bfloat16* __restrict__ gp, const __hip_bfloat16* bc,
                           const float* __restrict__ Lambda,
                           const float* __restrict__ carry_in,
                           const __hip_bfloat16* __restrict__ ab,
                           __hip_bfloat16* zb)
{
    const int c = blockIdx.y * 256 + threadIdx.x;
    const int j = blockIdx.x;
    const float cl = -8.f * log1pf(expf(Lambda[c]));
    float h = carry_in[j * 1024 + c];
    const int t0 = j * CL;
    for (int tt = 0; tt < CL; ++tt) {
        const int t = t0 + tt;
        const long gi = (long)t * 2048 + c;
        const long bi = (long)t * 1024 + c;
        const float ig = 1.f / (1.f + expf(-__bfloat162float(gp[gi])));
        const float rg = 1.f / (1.f + expf(-__bfloat162float(gp[gi + 1024])));
        const float a  = expf(cl * rg);
        const float gx = sqrtf(fmaxf(0.f, 1.f - a * a)) * ig * __bfloat162float(bc[bi]);
        h = fmaf(a, h, gx);
        zb[bi] = __float2bfloat16(__bfloat162float(ab[bi]) * h);
    }
}

extern "C" void kernel_launch(void* const* d_in, const int* in_sizes, int n_in,
                              void* d_out, int out_size, void* d_ws, size_t ws_size,
                              hipStream_t stream)
{
    const float* x      = (const float*)d_in[0];
    const float* w1     = (const float*)d_in[1];
    const float* b1     = (const float*)d_in[2];
    const float* conv_w = (const float*)d_in[3];
    const float* w_rg   = (const float*)d_in[4];
    const float* b_rg   = (const float*)d_in[5];
    const float* w_out  = (const float*)d_in[6];
    const float* b_out  = (const float*)d_in[7];
    const float* Lambda = (const float*)d_in[8];
    float* out = (float*)d_out;
    (void)in_sizes; (void)n_in; (void)out_size; (void)ws_size;

    // ---- workspace layout (~110 MB) ----
    char* p = (char*)d_ws;
    auto alloc = [&](size_t bytes) { char* r = p; p += (bytes + 255) & ~255ULL; return r; };
    __hip_bfloat16* gpre  = (__hip_bfloat16*)alloc(8192ULL * 2048 * 2); // 32 MB
    __hip_bfloat16* ab    = (__hip_bfloat16*)alloc(8192ULL * 1024 * 2); // 16 MB
    __hip_bfloat16* bbp   = (__hip_bfloat16*)alloc(8200ULL * 1024 * 2); // 16.8 MB
    __hip_bfloat16* bcb   = (__hip_bfloat16*)alloc(8192ULL * 1024 * 2); // 16 MB (later zb)
    __hip_bfloat16* wbigb = (__hip_bfloat16*)alloc(1024ULL * 4096 * 2); // 8 MB
    __hip_bfloat16* xb    = (__hip_bfloat16*)alloc(8192ULL * 768 * 2);  // 12 MB
    __hip_bfloat16* w1b   = (__hip_bfloat16*)alloc(2048ULL * 768 * 2);  // 3 MB
    __hip_bfloat16* w_rgb = (__hip_bfloat16*)alloc(2048ULL * 1024 * 2); // 4 MB
    __hip_bfloat16* w_outb= (__hip_bfloat16*)alloc(768ULL * 1024 * 2);  // 1.5 MB
    float*          chv   = (float*)alloc(NC * 1024ULL * 4);
    float*          cav   = (float*)alloc(NC * 1024ULL * 4);
    __hip_bfloat16* zb    = bcb;   // overlay

    prep_kernel<<<PREP_TOT / 256, 256, 0, stream>>>(x, w1, w_rg, w_out, conv_w,
                                                    xb, w1b, w_rgb, w_outb, wbigb, bbp);

    // h = x @ w1.T + b1, fused split: ab = bf16(gelu), bbp = bf16 (rows +3)
    {
        dim3 grid(T_LEN / 128, 2048 / 128);
        gemm_mfma<false, 2><<<grid, 256, 0, stream>>>(xb, w1b, b1, ab, DM, DM, 2048, bbp);
    }

    // bc = causal conv as GEMM (M=8192, N=1024, K=4096) -> bf16
    {
        dim3 grid(T_LEN / 128, 1024 / 128);
        gemm_mfma<true, 1><<<grid, 256, 0, stream>>>(bbp, wbigb, nullptr, bcb, 4 * DR, DR, DR, nullptr);
    }

    // g_pre = bc @ w_rg.T + b_rg -> bf16
    {
        dim3 grid(T_LEN / 128, 2048 / 128);
        gemm_mfma<false, 1><<<grid, 256, 0, stream>>>(bcb, w_rgb, b_rg, gpre, DR, DR, 2048, nullptr);
    }

    // chunked scan with fused gates; z = ab*y -> bf16 (overlays bcb)
    {
        dim3 gs(NC, DR / 256);
        scan_pass1<<<gs, 256, 0, stream>>>(gpre, bcb, Lambda, chv, cav);
        scan_combine<<<DR / 256, 256, 0, stream>>>(chv, cav);
        scan_pass2<<<gs, 256, 0, stream>>>(gpre, bcb, Lambda, chv, ab, zb);
    }

    // out = z @ w_out.T + b_out -> fp32
    {
        dim3 grid(T_LEN / 128, DM / 128);
        gemm_mfma<false, 0><<<grid, 256, 0, stream>>>(zb, w_outb, b_out, out, DR, DR, DM, nullptr);
    }
}